// Round 3
// baseline (110.554 us; speedup 1.0000x reference)
//
#include <hip/hip_runtime.h>
#include <hip/hip_bf16.h>
#include <math.h>

#define LN_EPS 1e-5f

constexpr int BB  = 4;
constexpr int NS  = 1024;
constexpr int KP  = 8192;
constexpr int DV  = 768;
constexpr int DC  = 256;

using bf16x8 = __attribute__((ext_vector_type(8))) short;
using f32x4  = __attribute__((ext_vector_type(4))) float;

static __device__ __forceinline__ unsigned short f2bf(float v) {
    __hip_bfloat16 h = __float2bfloat16(v);
    return *reinterpret_cast<unsigned short*>(&h);
}

// ---------------------------------------------------------------------------
// K1: blocks [0,512)   : argmin — 8 seeds/block, f64-exact ordering via the
//     monotone form |p|^2 - 2 s.p. NEW: the 13-bit point index is packed into
//     the low mantissa bits of the f64 score (perturbation 2^-39 relative —
//     far below the f32 input noise at which the reference argmin already
//     matches exact ordering), so min+argmin is a single v_min_f64 chain:
//     ~18 cy/pair vs 22 (3 FMA + and_or + min), and no idx registers.
//     blocks [512,832) : weight f32->bf16 conversion (1 float4/thread).
// ---------------------------------------------------------------------------
__global__ __launch_bounds__(256) void argmin_prep_kernel(
    const float* __restrict__ seed_xyz, const float* __restrict__ pts,
    int* __restrict__ out_idx,
    const float* __restrict__ Wp, const float* __restrict__ W1,
    const float* __restrict__ W2,
    unsigned short* __restrict__ Wpb, unsigned short* __restrict__ W1b,
    unsigned short* __restrict__ W2b)
{
    const int t = threadIdx.x;
    if (blockIdx.x >= 512) {
        int e  = (blockIdx.x - 512) * 256 + t;   // float4 id, 81920 total
        int e4 = e << 2;
        const float* src; unsigned short* dst; int off;
        if (e4 < DC * DV)              { src = Wp; dst = Wpb; off = e4; }
        else if (e4 < DC * (DV + DC))  { src = W1; dst = W1b; off = e4 - DC * DV; }
        else                           { src = W2; dst = W2b; off = e4 - DC * (DV + DC); }
        float4 v = *(const float4*)(src + off);
        ushort4 o;
        o.x = f2bf(v.x); o.y = f2bf(v.y); o.z = f2bf(v.z); o.w = f2bf(v.w);
        *(ushort4*)(dst + off) = o;
        return;
    }

    __shared__ float shX[1024], shY[1024], shZ[1024];
    __shared__ double rb[4][8];

    const int bid  = blockIdx.x;
    const int b    = bid >> 7;          // 128 tiles per batch
    const int tile = bid & 127;

    double n2sx[8], n2sy[8], n2sz[8];
    {
        const float* sp = seed_xyz + ((size_t)b * NS + tile * 8) * 3;
        #pragma unroll
        for (int ss = 0; ss < 8; ++ss) {
            n2sx[ss] = -2.0 * (double)sp[ss * 3 + 0];
            n2sy[ss] = -2.0 * (double)sp[ss * 3 + 1];
            n2sz[ss] = -2.0 * (double)sp[ss * 3 + 2];
        }
    }

    const float* pb = pts + (size_t)b * KP * 3;
    double best[8];
    #pragma unroll
    for (int ss = 0; ss < 8; ++ss) best[ss] = 1e300;

    for (int kt = 0; kt < KP; kt += 1024) {
        #pragma unroll
        for (int q = 0; q < 4; ++q) {
            int i = t + q * 256;
            const float* pp = pb + (size_t)(kt + i) * 3;
            shX[i] = pp[0]; shY[i] = pp[1]; shZ[i] = pp[2];
        }
        __syncthreads();
        #pragma unroll 2
        for (int q = 0; q < 4; ++q) {
            int kl = t + (q << 8);
            double px = (double)shX[kl];
            double py = (double)shY[kl];
            double pz = (double)shZ[kl];
            double h  = fma(px, px, fma(py, py, pz * pz));
            long long kidx = (long long)(kt + kl);
            #pragma unroll
            for (int ss = 0; ss < 8; ++ss) {
                double acc = fma(n2sx[ss], px, h);
                acc = fma(n2sy[ss], py, acc);
                acc = fma(n2sz[ss], pz, acc);
                long long bits = __double_as_longlong(acc);
                bits = (bits & 0xFFFFFFFFFFFFE000LL) | kidx;  // 1 v_and_or_b32
                best[ss] = fmin(best[ss], __longlong_as_double(bits));
            }
        }
        __syncthreads();
    }

    // intra-wave min reduce (keys carry idx; no tie handling needed)
    #pragma unroll
    for (int o = 1; o < 64; o <<= 1) {
        #pragma unroll
        for (int ss = 0; ss < 8; ++ss)
            best[ss] = fmin(best[ss], __shfl_xor(best[ss], o));
    }
    const int w = t >> 6, l = t & 63;
    if (l == 0) {
        #pragma unroll
        for (int ss = 0; ss < 8; ++ss) rb[w][ss] = best[ss];
    }
    __syncthreads();
    if (t < 8) {
        double bb = rb[0][t];
        #pragma unroll
        for (int ww = 1; ww < 4; ++ww) bb = fmin(bb, rb[ww][t]);
        out_idx[b * NS + tile * 8 + t] =
            (int)(__double_as_longlong(bb) & 0x1FFFLL);
    }
}

// ---------------------------------------------------------------------------
// K2: fused projection + LN + adapter + blend (mega absorbed).
// Phase 1 (GEMM1): X_all = Wp(bf16) @ feat(bf16-on-the-fly) for this block's
//   64-wide k-tile, feat read fully coalesced. LDS B-tile is DOUBLE-BUFFERED
//   (1 barrier/step) with a 2-step-deep feat prefetch.
// Phase 2: each seed whose argmin k lands in this tile has its COMPLETE
//   256-ch X row inside this block's accumulators -> process owned seeds in
//   16-wide chunks entirely in-block: scatter accs to LDS XF, then the exact
//   mega code path (bias+LN+GEMM2+GEMM3+blend), lane/reduction order
//   identical => bitwise-identical output. No Xg round-trip, no mega kernel.
// grid = 4 b x 128 k-tiles = 512 blocks, 512 thr, 2 blocks/CU.
// ---------------------------------------------------------------------------
__global__ __launch_bounds__(512, 4) void projmega_kernel(
    const float* __restrict__ feat, const int* __restrict__ idx,
    const unsigned short* __restrict__ Wpb, const float* __restrict__ bp,
    const unsigned short* __restrict__ W1b, const float* __restrict__ b1,
    const unsigned short* __restrict__ W2b, const float* __restrict__ b2,
    const float* __restrict__ fg, float* __restrict__ out)
{
    // LDSB (dbuf, 10240 B) and XF (16x260 f32, 16640 B) are phase-disjoint.
    __shared__ alignas(16) char ubuf[16 * 260 * 4];
    unsigned short* LDSB = (unsigned short*)ubuf;   // [2][64*40]
    float*          XF   = (float*)ubuf;            // [16][260]
    __shared__ int ent_s[1024];
    __shared__ int ent_k[1024];
    __shared__ int nent;
    __shared__ alignas(16) unsigned short XT[16][264];
    __shared__ alignas(16) unsigned short HT[16][264];
    __shared__ float LNs[8][16];
    __shared__ float LNq[8][16];

    const int bid = blockIdx.x;
    const int b   = bid >> 7;
    const int kt  = bid & 127;
    const int k0  = kt * 64;
    const int t   = threadIdx.x;
    const int w   = t >> 6;
    const int l   = t & 63;
    const int col = l & 15;
    const int kq  = l >> 4;

    if (t == 0) nent = 0;
    __syncthreads();
    {   // owned-seed list for this k-tile
        int ka = idx[b * NS + t];
        int kb = idx[b * NS + 512 + t];
        if (ka >= k0 && ka < k0 + 64) { int p = atomicAdd(&nent, 1); ent_s[p] = t;       ent_k[p] = ka; }
        if (kb >= k0 && kb < k0 + 64) { int p = atomicAdd(&nent, 1); ent_s[p] = 512 + t; ent_k[p] = kb; }
    }

    // staging map: cc = t>>4 (32 c-rows/step), k4 = t&15 -> 1 float4 of k
    const int cc = t >> 4;
    const int k4 = t & 15;
    const float* fbase = feat + ((size_t)b * DV + cc) * KP + k0 + k4 * 4;

    f32x4 acc0[4], acc1[4];
    #pragma unroll
    for (int kg = 0; kg < 4; ++kg) {
        acc0[kg] = (f32x4){0.f, 0.f, 0.f, 0.f};
        acc1[kg] = (f32x4){0.f, 0.f, 0.f, 0.f};
    }

    // stage step-0 into buf0; prefetch step-1
    f32x4 r = *(const f32x4*)(fbase);
    {
        const int kr0 = k4 * 4, cb = cc >> 3, cl = cc & 7;
        #pragma unroll
        for (int i = 0; i < 4; ++i) {
            int krow = kr0 + i;
            int qv   = ((krow >> 2) ^ (krow >> 4)) & 3;
            LDSB[krow * 40 + ((cb ^ qv) << 3) + cl] = f2bf(r[i]);
        }
    }
    r = *(const f32x4*)(fbase + (size_t)32 * KP);
    __syncthreads();                    // buf0 + ent list visible

    // fg prefetch for chunk 0 (latency hidden under the whole GEMM)
    const float* fgb = fg + (size_t)b * DC * NS;
    float fgp[8];
    const int neE = nent;
    if (neE > 0) {
        int sd0 = ent_s[(col < neE) ? col : 0];
        #pragma unroll
        for (int rr = 0; rr < 4; ++rr) {
            int ch0 = w * 32 + kq * 4 + rr;
            fgp[rr]     = fgb[(size_t)ch0 * NS + sd0];
            fgp[4 + rr] = fgb[(size_t)(ch0 + 16) * NS + sd0];
        }
    }

    // ---- GEMM1 K-loop: 24 steps, double-buffered, 1 barrier/step ----
    for (int s = 0; s < 24; ++s) {
        if (s + 1 < 24) {               // stage next into other buffer
            const int kr0 = k4 * 4, cb = cc >> 3, cl = cc & 7;
            unsigned short* Lb = LDSB + ((s + 1) & 1) * (64 * 40);
            #pragma unroll
            for (int i = 0; i < 4; ++i) {
                int krow = kr0 + i;
                int qv   = ((krow >> 2) ^ (krow >> 4)) & 3;
                Lb[krow * 40 + ((cb ^ qv) << 3) + cl] = f2bf(r[i]);
            }
        }
        if (s + 2 < 24)
            r = *(const f32x4*)(fbase + (size_t)(s + 2) * 32 * KP);

        const unsigned short* A0 = Wpb + (size_t)(w * 32 + col) * DV + s * 32 + kq * 8;
        bf16x8 a0 = *(const bf16x8*)A0;
        bf16x8 a1 = *(const bf16x8*)(A0 + (size_t)16 * DV);
        const unsigned short* Lr = LDSB + (s & 1) * (64 * 40);
        #pragma unroll
        for (int kg = 0; kg < 4; ++kg) {
            int krow = kg * 16 + col;
            int qv   = ((krow >> 2) ^ (krow >> 4)) & 3;
            bf16x8 bf = *(const bf16x8*)&Lr[krow * 40 + ((kq ^ qv) << 3)];
            acc0[kg] = __builtin_amdgcn_mfma_f32_16x16x32_bf16(a0, bf, acc0[kg], 0, 0, 0);
            acc1[kg] = __builtin_amdgcn_mfma_f32_16x16x32_bf16(a1, bf, acc1[kg], 0, 0, 0);
        }
        __syncthreads();
    }

    // ---- Phase 2: per owned-seed chunk of 16: scatter->XF, then mega path ----
    const int ne = neE;
    for (int e0 = 0; e0 < ne; e0 += 16) {
        __syncthreads();                 // previous chunk's XF/XT/HT reads done
        const int nc = (ne - e0 < 16) ? (ne - e0) : 16;

        // producers: owner lanes write this chunk's X rows into XF [16][260]
        for (int e = e0; e < e0 + nc; ++e) {
            int kk = ent_k[e] - k0;
            if (col == (kk & 15)) {
                int j = kk >> 4;
                float* dst = XF + (e - e0) * 260 + w * 32 + kq * 4;
                #pragma unroll
                for (int jj = 0; jj < 4; ++jj) if (jj == j) {
                    *(f32x4*)dst        = acc0[jj];
                    *(f32x4*)(dst + 16) = acc1[jj];
                }
            }
        }
        __syncthreads();

        const bool valid = (col < nc);
        const int  sd    = ent_s[e0 + (valid ? col : 0)];

        float fgv[8];
        if (e0 == 0) {
            #pragma unroll
            for (int rr = 0; rr < 8; ++rr) fgv[rr] = fgp[rr];
        } else {
            #pragma unroll
            for (int rr = 0; rr < 4; ++rr) {
                int ch0 = w * 32 + kq * 4 + rr;
                fgv[rr]     = fgb[(size_t)ch0 * NS + sd];
                fgv[4 + rr] = fgb[(size_t)(ch0 + 16) * NS + sd];
            }
        }

        // X values for this thread's 8 (seed=col, ch) slots (== old Xg read)
        const float* xr = XF + col * 260 + w * 32 + kq * 4;
        f32x4 x0 = *(const f32x4*)xr;
        f32x4 x1 = *(const f32x4*)(xr + 16);

        // ---- bias + LayerNorm (order identical to previous mega) ----
        float vals[8];
        float s = 0.f, q = 0.f;
        #pragma unroll
        for (int rr = 0; rr < 4; ++rr) {
            int ch0 = w * 32 + kq * 4 + rr;
            float v0 = x0[rr] + bp[ch0];
            float v1 = x1[rr] + bp[ch0 + 16];
            vals[rr]     = v0;
            vals[4 + rr] = v1;
            s += v0 + v1;
            q += v0 * v0 + v1 * v1;
        }
        s += __shfl_xor(s, 16); s += __shfl_xor(s, 32);
        q += __shfl_xor(q, 16); q += __shfl_xor(q, 32);
        if (l < 16) { LNs[w][l] = s; LNq[w][l] = q; }
        __syncthreads();
        float S = 0.f, Q = 0.f;
        #pragma unroll
        for (int ww = 0; ww < 8; ++ww) { S += LNs[ww][col]; Q += LNq[ww][col]; }
        float mu   = S * (1.0f / DC);
        float rstd = rsqrtf(Q * (1.0f / DC) - mu * mu + LN_EPS);
        {
            ushort4 p0, p1;
            p0.x = f2bf((vals[0] - mu) * rstd);
            p0.y = f2bf((vals[1] - mu) * rstd);
            p0.z = f2bf((vals[2] - mu) * rstd);
            p0.w = f2bf((vals[3] - mu) * rstd);
            p1.x = f2bf((vals[4] - mu) * rstd);
            p1.y = f2bf((vals[5] - mu) * rstd);
            p1.z = f2bf((vals[6] - mu) * rstd);
            p1.w = f2bf((vals[7] - mu) * rstd);
            *(ushort4*)&XT[col][w * 32 + kq * 4]      = p0;
            *(ushort4*)&XT[col][w * 32 + 16 + kq * 4] = p1;
        }
        __syncthreads();

        // ---- GEMM2: H = relu(W1 @ X_ln + b1) ----
        f32x4 c0 = {0.f, 0.f, 0.f, 0.f};
        f32x4 c1 = {0.f, 0.f, 0.f, 0.f};
        {
            const unsigned short* A0 = W1b + (size_t)(w * 32 + col) * DC;
            const unsigned short* A1 = W1b + (size_t)(w * 32 + 16 + col) * DC;
            #pragma unroll
            for (int ks = 0; ks < 8; ++ks) {
                int kb = ks * 32 + kq * 8;
                bf16x8 bf = *(const bf16x8*)&XT[col][kb];
                bf16x8 a0 = *(const bf16x8*)&A0[kb];
                bf16x8 a1 = *(const bf16x8*)&A1[kb];
                c0 = __builtin_amdgcn_mfma_f32_16x16x32_bf16(a0, bf, c0, 0, 0, 0);
                c1 = __builtin_amdgcn_mfma_f32_16x16x32_bf16(a1, bf, c1, 0, 0, 0);
            }
        }
        {
            ushort4 p0, p1;
            int ch0 = w * 32 + kq * 4;
            p0.x = f2bf(fmaxf(c0[0] + b1[ch0 + 0], 0.f));
            p0.y = f2bf(fmaxf(c0[1] + b1[ch0 + 1], 0.f));
            p0.z = f2bf(fmaxf(c0[2] + b1[ch0 + 2], 0.f));
            p0.w = f2bf(fmaxf(c0[3] + b1[ch0 + 3], 0.f));
            p1.x = f2bf(fmaxf(c1[0] + b1[ch0 + 16], 0.f));
            p1.y = f2bf(fmaxf(c1[1] + b1[ch0 + 17], 0.f));
            p1.z = f2bf(fmaxf(c1[2] + b1[ch0 + 18], 0.f));
            p1.w = f2bf(fmaxf(c1[3] + b1[ch0 + 19], 0.f));
            *(ushort4*)&HT[col][ch0]      = p0;
            *(ushort4*)&HT[col][ch0 + 16] = p1;
        }
        __syncthreads();

        // ---- GEMM3 + blend + scattered store ----
        c0 = (f32x4){0.f, 0.f, 0.f, 0.f};
        c1 = (f32x4){0.f, 0.f, 0.f, 0.f};
        {
            const unsigned short* A0 = W2b + (size_t)(w * 32 + col) * DC;
            const unsigned short* A1 = W2b + (size_t)(w * 32 + 16 + col) * DC;
            #pragma unroll
            for (int ks = 0; ks < 8; ++ks) {
                int kb = ks * 32 + kq * 8;
                bf16x8 bf = *(const bf16x8*)&HT[col][kb];
                bf16x8 a0 = *(const bf16x8*)&A0[kb];
                bf16x8 a1 = *(const bf16x8*)&A1[kb];
                c0 = __builtin_amdgcn_mfma_f32_16x16x32_bf16(a0, bf, c0, 0, 0, 0);
                c1 = __builtin_amdgcn_mfma_f32_16x16x32_bf16(a1, bf, c1, 0, 0, 0);
            }
        }
        if (valid) {
            float* ob = out + (size_t)b * DC * NS;
            #pragma unroll
            for (int rr = 0; rr < 4; ++rr) {
                int ch0 = w * 32 + kq * 4 + rr;
                int ch1 = ch0 + 16;
                ob[(size_t)ch0 * NS + sd] = 0.5f * fgv[rr]     + 0.5f * (c0[rr] + b2[ch0]);
                ob[(size_t)ch1 * NS + sd] = 0.5f * fgv[4 + rr] + 0.5f * (c1[rr] + b2[ch1]);
            }
        }
    }
}

extern "C" void kernel_launch(void* const* d_in, const int* in_sizes, int n_in,
                              void* d_out, int out_size, void* d_ws, size_t ws_size,
                              hipStream_t stream)
{
    (void)in_sizes; (void)n_in; (void)out_size; (void)ws_size;
    const float* seed_xyz = (const float*)d_in[1];
    const float* pts      = (const float*)d_in[2];
    const float* feat     = (const float*)d_in[3];
    const float* fgn      = (const float*)d_in[4];
    const float* Wp       = (const float*)d_in[5];
    const float* bp       = (const float*)d_in[6];
    const float* W1       = (const float*)d_in[7];
    const float* b1       = (const float*)d_in[8];
    const float* W2       = (const float*)d_in[9];
    const float* b2       = (const float*)d_in[10];
    float* out = (float*)d_out;

    // workspace layout (16B aligned):
    //   idx  @ 0        (16 KB)
    //   Wpb  @ 16384    (384 KB)
    //   W1b  @ 409600   (128 KB)
    //   W2b  @ 540672   (128 KB)
    char* ws = (char*)d_ws;
    int*            idx = (int*)ws;
    unsigned short* Wpb = (unsigned short*)(ws + 16384);
    unsigned short* W1b = (unsigned short*)(ws + 409600);
    unsigned short* W2b = (unsigned short*)(ws + 540672);

    argmin_prep_kernel<<<dim3(832), dim3(256), 0, stream>>>(
        seed_xyz, pts, idx, Wp, W1, W2, Wpb, W1b, W2b);
    projmega_kernel<<<dim3(512), dim3(512), 0, stream>>>(
        feat, idx, Wpb, bp, W1b, b1, W2b, b2, fgn, out);
}

// Round 4
// 102.682 us; speedup vs baseline: 1.0767x; 1.0767x over previous
//
#include <hip/hip_runtime.h>
#include <hip/hip_bf16.h>
#include <math.h>

#define LN_EPS 1e-5f

constexpr int BB  = 4;
constexpr int NS  = 1024;
constexpr int KP  = 8192;
constexpr int DV  = 768;
constexpr int DC  = 256;

using bf16x8 = __attribute__((ext_vector_type(8))) short;
using f32x4  = __attribute__((ext_vector_type(4))) float;

static __device__ __forceinline__ unsigned short f2bf(float v) {
    __hip_bfloat16 h = __float2bfloat16(v);
    return *reinterpret_cast<unsigned short*>(&h);
}

// ---------------------------------------------------------------------------
// K1: blocks [0,512)   : argmin — 8 seeds/block, f64-exact ordering via the
//     monotone form |p|^2 - 2 s.p with the 13-bit point index packed into the
//     low mantissa bits (perturbation 2^-39 relative), so min+argmin is a
//     plain v_min_f64 chain.
//     blocks [512,832) : weight f32->bf16 conversion (1 float4/thread).
// ---------------------------------------------------------------------------
__global__ __launch_bounds__(256) void argmin_prep_kernel(
    const float* __restrict__ seed_xyz, const float* __restrict__ pts,
    int* __restrict__ out_idx,
    const float* __restrict__ Wp, const float* __restrict__ W1,
    const float* __restrict__ W2,
    unsigned short* __restrict__ Wpb, unsigned short* __restrict__ W1b,
    unsigned short* __restrict__ W2b)
{
    const int t = threadIdx.x;
    if (blockIdx.x >= 512) {
        int e  = (blockIdx.x - 512) * 256 + t;   // float4 id, 81920 total
        int e4 = e << 2;
        const float* src; unsigned short* dst; int off;
        if (e4 < DC * DV)              { src = Wp; dst = Wpb; off = e4; }
        else if (e4 < DC * (DV + DC))  { src = W1; dst = W1b; off = e4 - DC * DV; }
        else                           { src = W2; dst = W2b; off = e4 - DC * (DV + DC); }
        float4 v = *(const float4*)(src + off);
        ushort4 o;
        o.x = f2bf(v.x); o.y = f2bf(v.y); o.z = f2bf(v.z); o.w = f2bf(v.w);
        *(ushort4*)(dst + off) = o;
        return;
    }

    __shared__ float shX[1024], shY[1024], shZ[1024];
    __shared__ double rb[4][8];

    const int bid  = blockIdx.x;
    const int b    = bid >> 7;          // 128 tiles per batch
    const int tile = bid & 127;

    double n2sx[8], n2sy[8], n2sz[8];
    {
        const float* sp = seed_xyz + ((size_t)b * NS + tile * 8) * 3;
        #pragma unroll
        for (int ss = 0; ss < 8; ++ss) {
            n2sx[ss] = -2.0 * (double)sp[ss * 3 + 0];
            n2sy[ss] = -2.0 * (double)sp[ss * 3 + 1];
            n2sz[ss] = -2.0 * (double)sp[ss * 3 + 2];
        }
    }

    const float* pb = pts + (size_t)b * KP * 3;
    double best[8];
    #pragma unroll
    for (int ss = 0; ss < 8; ++ss) best[ss] = 1e300;

    for (int kt = 0; kt < KP; kt += 1024) {
        #pragma unroll
        for (int q = 0; q < 4; ++q) {
            int i = t + q * 256;
            const float* pp = pb + (size_t)(kt + i) * 3;
            shX[i] = pp[0]; shY[i] = pp[1]; shZ[i] = pp[2];
        }
        __syncthreads();
        #pragma unroll 2
        for (int q = 0; q < 4; ++q) {
            int kl = t + (q << 8);
            double px = (double)shX[kl];
            double py = (double)shY[kl];
            double pz = (double)shZ[kl];
            double h  = fma(px, px, fma(py, py, pz * pz));
            long long kidx = (long long)(kt + kl);
            #pragma unroll
            for (int ss = 0; ss < 8; ++ss) {
                double acc = fma(n2sx[ss], px, h);
                acc = fma(n2sy[ss], py, acc);
                acc = fma(n2sz[ss], pz, acc);
                long long bits = __double_as_longlong(acc);
                bits = (bits & 0xFFFFFFFFFFFFE000LL) | kidx;
                best[ss] = fmin(best[ss], __longlong_as_double(bits));
            }
        }
        __syncthreads();
    }

    #pragma unroll
    for (int o = 1; o < 64; o <<= 1) {
        #pragma unroll
        for (int ss = 0; ss < 8; ++ss)
            best[ss] = fmin(best[ss], __shfl_xor(best[ss], o));
    }
    const int w = t >> 6, l = t & 63;
    if (l == 0) {
        #pragma unroll
        for (int ss = 0; ss < 8; ++ss) rb[w][ss] = best[ss];
    }
    __syncthreads();
    if (t < 8) {
        double bb = rb[0][t];
        #pragma unroll
        for (int ww = 1; ww < 4; ++ww) bb = fmin(bb, rb[ww][t]);
        out_idx[b * NS + tile * 8 + t] =
            (int)(__double_as_longlong(bb) & 0x1FFFLL);
    }
}

// ---------------------------------------------------------------------------
// K2: sieve — contiguous stream of feat with on-the-fly column selection.
// grid = 4 b x 4 k-slabs(2048) x 16 c-groups(48 rows) = 256 blocks, 512 thr.
// Per step ALL 512 threads read ONE feat row of this slab (8 KB contiguous,
// 1 float4/thread) — pure streaming DRAM pattern; 8-deep register prefetch
// (128 B/thread in flight). Selection is row-invariant: thread t owns k =
// 4t..4t+3; chain heads for those k (seeds sharing an argmin k are chained
// via nxt[]) are hoisted to registers, so the per-row cost is 4 register
// compares + rare bf16 writes Gb[b][seed][c] (identical f2bf rounding to the
// old gather -> mega path bitwise unchanged).
// ---------------------------------------------------------------------------
__global__ __launch_bounds__(512) void sieve_kernel(
    const float* __restrict__ feat, const int* __restrict__ idx,
    unsigned short* __restrict__ Gb)
{
    __shared__ int head[2048];
    __shared__ int nxt[1024];

    const int bid = blockIdx.x;
    const int b   = bid >> 6;
    const int sl  = (bid >> 4) & 3;
    const int cg  = bid & 15;
    const int k0  = sl * 2048;
    const int c0  = cg * 48;
    const int t   = threadIdx.x;

    #pragma unroll
    for (int i = 0; i < 4; ++i) head[t + i * 512] = -1;
    __syncthreads();
    #pragma unroll
    for (int i = 0; i < 2; ++i) {
        int sd = t + i * 512;
        int k  = idx[b * NS + sd];
        if (k >= k0 && k < k0 + 2048)
            nxt[sd] = atomicExch(&head[k - k0], sd);
    }
    __syncthreads();

    // row-invariant chain heads for this thread's 4 k positions
    const int e0 = head[t * 4 + 0];
    const int e1 = head[t * 4 + 1];
    const int e2 = head[t * 4 + 2];
    const int e3 = head[t * 4 + 3];

    const float* fb = feat + ((size_t)(b * DV + c0)) * KP + k0 + t * 4;
    unsigned short* gb = Gb + (size_t)b * NS * DV + c0;

    auto proc = [&](f32x4 v, int r) {
        int e;
        e = e0; while (e >= 0) { gb[(size_t)e * DV + r] = f2bf(v[0]); e = nxt[e]; }
        e = e1; while (e >= 0) { gb[(size_t)e * DV + r] = f2bf(v[1]); e = nxt[e]; }
        e = e2; while (e >= 0) { gb[(size_t)e * DV + r] = f2bf(v[2]); e = nxt[e]; }
        e = e3; while (e >= 0) { gb[(size_t)e * DV + r] = f2bf(v[3]); e = nxt[e]; }
    };
    auto ld = [&](int r) -> f32x4 {
        return *(const f32x4*)(fb + (size_t)r * KP);
    };

    // 48 rows, 8-deep software pipeline (named regs: no dynamic indexing)
    f32x4 v0 = ld(0), v1 = ld(1), v2 = ld(2), v3 = ld(3);
    f32x4 v4 = ld(4), v5 = ld(5), v6 = ld(6), v7 = ld(7);
    for (int r = 0; r < 48; r += 8) {
        proc(v0, r + 0); if (r +  8 < 48) v0 = ld(r +  8);
        proc(v1, r + 1); if (r +  9 < 48) v1 = ld(r +  9);
        proc(v2, r + 2); if (r + 10 < 48) v2 = ld(r + 10);
        proc(v3, r + 3); if (r + 11 < 48) v3 = ld(r + 11);
        proc(v4, r + 4); if (r + 12 < 48) v4 = ld(r + 12);
        proc(v5, r + 5); if (r + 13 < 48) v5 = ld(r + 13);
        proc(v6, r + 6); if (r + 14 < 48) v6 = ld(r + 14);
        proc(v7, r + 7); if (r + 15 < 48) v7 = ld(r + 15);
    }
}

// ---------------------------------------------------------------------------
// K3: mega GEMM chain (verified R1 version). per block = (batch, 16 seeds),
// 8 waves. MFMA frag: A row=lane&15,k=(lane>>4)*8+j ; B col=lane&15;
// C/D col=lane&15, row=(lane>>4)*4+reg. fg blend operand prefetched at
// kernel start so its HBM latency hides under the whole GEMM chain.
// ---------------------------------------------------------------------------
__global__ __launch_bounds__(512) void mega_kernel(
    const unsigned short* __restrict__ Gb,
    const float* __restrict__ fg,
    const unsigned short* __restrict__ Wpb, const float* __restrict__ bp,
    const unsigned short* __restrict__ W1b, const float* __restrict__ b1,
    const unsigned short* __restrict__ W2b, const float* __restrict__ b2,
    float* __restrict__ out)
{
    __shared__ alignas(16) unsigned short GtT[16][776];
    __shared__ alignas(16) unsigned short XT[16][264];
    __shared__ alignas(16) unsigned short HT[16][264];
    __shared__ float LNs[8][16];
    __shared__ float LNq[8][16];

    const int bid  = blockIdx.x;
    const int b    = bid >> 6;
    const int tile = bid & 63;
    const int n0   = tile * 16;
    const int t    = threadIdx.x;
    const int w    = t >> 6;
    const int l    = t & 63;
    const int col  = l & 15;
    const int kq   = l >> 4;

    // prefetch blend operand (consumed in epilogue; latency hidden)
    const float* fgb = fg + (size_t)b * DC * NS;
    float fgv[8];
    #pragma unroll
    for (int r = 0; r < 4; ++r) {
        int ch0 = w * 32 + kq * 4 + r;
        fgv[r]     = fgb[(size_t)ch0 * NS + n0 + col];
        fgv[4 + r] = fgb[(size_t)(ch0 + 16) * NS + n0 + col];
    }

    for (int i = t; i < 1536; i += 512) {
        int row = i / 96, c8 = (i % 96) * 8;
        *(bf16x8*)&GtT[row][c8] =
            *(const bf16x8*)&Gb[((size_t)b * NS + n0 + row) * DV + c8];
    }
    __syncthreads();

    // ---- GEMM1: K = 768 ----
    f32x4 acc0 = {0.f, 0.f, 0.f, 0.f};
    f32x4 acc1 = {0.f, 0.f, 0.f, 0.f};
    {
        const unsigned short* A0 = Wpb + (size_t)(w * 32 + col) * DV;
        const unsigned short* A1 = Wpb + (size_t)(w * 32 + 16 + col) * DV;
        #pragma unroll 4
        for (int ks = 0; ks < 24; ++ks) {
            int kb = ks * 32 + kq * 8;
            bf16x8 bf = *(const bf16x8*)&GtT[col][kb];
            bf16x8 a0 = *(const bf16x8*)&A0[kb];
            bf16x8 a1 = *(const bf16x8*)&A1[kb];
            acc0 = __builtin_amdgcn_mfma_f32_16x16x32_bf16(a0, bf, acc0, 0, 0, 0);
            acc1 = __builtin_amdgcn_mfma_f32_16x16x32_bf16(a1, bf, acc1, 0, 0, 0);
        }
    }

    // ---- bias + LayerNorm over channels ----
    float vals[8];
    float s = 0.f, q = 0.f;
    #pragma unroll
    for (int r = 0; r < 4; ++r) {
        int ch0 = w * 32 + kq * 4 + r;
        float v0 = acc0[r] + bp[ch0];
        float v1 = acc1[r] + bp[ch0 + 16];
        vals[r]     = v0;
        vals[4 + r] = v1;
        s += v0 + v1;
        q += v0 * v0 + v1 * v1;
    }
    s += __shfl_xor(s, 16); s += __shfl_xor(s, 32);
    q += __shfl_xor(q, 16); q += __shfl_xor(q, 32);
    if (l < 16) { LNs[w][l] = s; LNq[w][l] = q; }
    __syncthreads();
    float S = 0.f, Q = 0.f;
    #pragma unroll
    for (int ww = 0; ww < 8; ++ww) { S += LNs[ww][col]; Q += LNq[ww][col]; }
    float mu   = S * (1.0f / DC);
    float rstd = rsqrtf(Q * (1.0f / DC) - mu * mu + LN_EPS);
    {
        ushort4 p0, p1;
        p0.x = f2bf((vals[0] - mu) * rstd);
        p0.y = f2bf((vals[1] - mu) * rstd);
        p0.z = f2bf((vals[2] - mu) * rstd);
        p0.w = f2bf((vals[3] - mu) * rstd);
        p1.x = f2bf((vals[4] - mu) * rstd);
        p1.y = f2bf((vals[5] - mu) * rstd);
        p1.z = f2bf((vals[6] - mu) * rstd);
        p1.w = f2bf((vals[7] - mu) * rstd);
        *(ushort4*)&XT[col][w * 32 + kq * 4]      = p0;
        *(ushort4*)&XT[col][w * 32 + 16 + kq * 4] = p1;
    }
    __syncthreads();

    // ---- GEMM2: H = relu(W1 @ X_ln + b1) ----
    acc0 = (f32x4){0.f, 0.f, 0.f, 0.f};
    acc1 = (f32x4){0.f, 0.f, 0.f, 0.f};
    {
        const unsigned short* A0 = W1b + (size_t)(w * 32 + col) * DC;
        const unsigned short* A1 = W1b + (size_t)(w * 32 + 16 + col) * DC;
        #pragma unroll
        for (int ks = 0; ks < 8; ++ks) {
            int kb = ks * 32 + kq * 8;
            bf16x8 bf = *(const bf16x8*)&XT[col][kb];
            bf16x8 a0 = *(const bf16x8*)&A0[kb];
            bf16x8 a1 = *(const bf16x8*)&A1[kb];
            acc0 = __builtin_amdgcn_mfma_f32_16x16x32_bf16(a0, bf, acc0, 0, 0, 0);
            acc1 = __builtin_amdgcn_mfma_f32_16x16x32_bf16(a1, bf, acc1, 0, 0, 0);
        }
    }
    {
        ushort4 p0, p1;
        int ch0 = w * 32 + kq * 4;
        p0.x = f2bf(fmaxf(acc0[0] + b1[ch0 + 0], 0.f));
        p0.y = f2bf(fmaxf(acc0[1] + b1[ch0 + 1], 0.f));
        p0.z = f2bf(fmaxf(acc0[2] + b1[ch0 + 2], 0.f));
        p0.w = f2bf(fmaxf(acc0[3] + b1[ch0 + 3], 0.f));
        p1.x = f2bf(fmaxf(acc1[0] + b1[ch0 + 16], 0.f));
        p1.y = f2bf(fmaxf(acc1[1] + b1[ch0 + 17], 0.f));
        p1.z = f2bf(fmaxf(acc1[2] + b1[ch0 + 18], 0.f));
        p1.w = f2bf(fmaxf(acc1[3] + b1[ch0 + 19], 0.f));
        *(ushort4*)&HT[col][ch0]      = p0;
        *(ushort4*)&HT[col][ch0 + 16] = p1;
    }
    __syncthreads();

    // ---- GEMM3 + blend + store ----
    acc0 = (f32x4){0.f, 0.f, 0.f, 0.f};
    acc1 = (f32x4){0.f, 0.f, 0.f, 0.f};
    {
        const unsigned short* A0 = W2b + (size_t)(w * 32 + col) * DC;
        const unsigned short* A1 = W2b + (size_t)(w * 32 + 16 + col) * DC;
        #pragma unroll
        for (int ks = 0; ks < 8; ++ks) {
            int kb = ks * 32 + kq * 8;
            bf16x8 bf = *(const bf16x8*)&HT[col][kb];
            bf16x8 a0 = *(const bf16x8*)&A0[kb];
            bf16x8 a1 = *(const bf16x8*)&A1[kb];
            acc0 = __builtin_amdgcn_mfma_f32_16x16x32_bf16(a0, bf, acc0, 0, 0, 0);
            acc1 = __builtin_amdgcn_mfma_f32_16x16x32_bf16(a1, bf, acc1, 0, 0, 0);
        }
    }
    {
        float* ob = out + (size_t)b * DC * NS;
        #pragma unroll
        for (int r = 0; r < 4; ++r) {
            int ch0 = w * 32 + kq * 4 + r;
            int ch1 = ch0 + 16;
            size_t o0 = (size_t)ch0 * NS + n0 + col;
            size_t o1 = (size_t)ch1 * NS + n0 + col;
            ob[o0] = 0.5f * fgv[r]     + 0.5f * (acc0[r] + b2[ch0]);
            ob[o1] = 0.5f * fgv[4 + r] + 0.5f * (acc1[r] + b2[ch1]);
        }
    }
}

extern "C" void kernel_launch(void* const* d_in, const int* in_sizes, int n_in,
                              void* d_out, int out_size, void* d_ws, size_t ws_size,
                              hipStream_t stream)
{
    (void)in_sizes; (void)n_in; (void)out_size; (void)ws_size;
    const float* seed_xyz = (const float*)d_in[1];
    const float* pts      = (const float*)d_in[2];
    const float* feat     = (const float*)d_in[3];
    const float* fgn      = (const float*)d_in[4];
    const float* Wp       = (const float*)d_in[5];
    const float* bp       = (const float*)d_in[6];
    const float* W1       = (const float*)d_in[7];
    const float* b1       = (const float*)d_in[8];
    const float* W2       = (const float*)d_in[9];
    const float* b2       = (const float*)d_in[10];
    float* out = (float*)d_out;

    // workspace layout (16B aligned):
    //   idx  @ 0        (16 KB)
    //   Wpb  @ 16384    (384 KB)
    //   W1b  @ 409600   (128 KB)
    //   W2b  @ 540672   (128 KB)
    //   Gb   @ 671744   (6.29 MB bf16 [B][NS][DV])
    char* ws = (char*)d_ws;
    int*            idx = (int*)ws;
    unsigned short* Wpb = (unsigned short*)(ws + 16384);
    unsigned short* W1b = (unsigned short*)(ws + 409600);
    unsigned short* W2b = (unsigned short*)(ws + 540672);
    unsigned short* Gb  = (unsigned short*)(ws + 671744);

    argmin_prep_kernel<<<dim3(832), dim3(256), 0, stream>>>(
        seed_xyz, pts, idx, Wp, W1, W2, Wpb, W1b, W2b);
    sieve_kernel<<<dim3(256), dim3(512), 0, stream>>>(feat, idx, Gb);
    mega_kernel<<<dim3(BB * (NS / 16)), dim3(512), 0, stream>>>(
        Gb, fgn, Wpb, bp, W1b, b1, W2b, b2, out);
}

// Round 5
// 70.036 us; speedup vs baseline: 1.5785x; 1.4661x over previous
//
#include <hip/hip_runtime.h>
#include <hip/hip_bf16.h>
#include <math.h>

#define LN_EPS 1e-5f

constexpr int BB  = 4;
constexpr int NS  = 1024;
constexpr int KP  = 8192;
constexpr int DV  = 768;
constexpr int DC  = 256;

using bf16x8 = __attribute__((ext_vector_type(8))) short;
using f32x4  = __attribute__((ext_vector_type(4))) float;

static __device__ __forceinline__ unsigned short f2bf(float v) {
    __hip_bfloat16 h = __float2bfloat16(v);
    return *reinterpret_cast<unsigned short*>(&h);
}

// ---------------------------------------------------------------------------
// K1: blocks [0,512)   : argmin — 8 seeds/block, f64-exact ordering via the
//     monotone form |p|^2 - 2 s.p with the 13-bit point index packed into the
//     low mantissa bits (perturbation 2^-39 relative), so min+argmin is a
//     plain v_min_f64 chain.
//     blocks [512,832) : weight f32->bf16 conversion (1 float4/thread).
//     (verified; unchanged)
// ---------------------------------------------------------------------------
__global__ __launch_bounds__(256) void argmin_prep_kernel(
    const float* __restrict__ seed_xyz, const float* __restrict__ pts,
    int* __restrict__ out_idx,
    const float* __restrict__ Wp, const float* __restrict__ W1,
    const float* __restrict__ W2,
    unsigned short* __restrict__ Wpb, unsigned short* __restrict__ W1b,
    unsigned short* __restrict__ W2b)
{
    const int t = threadIdx.x;
    if (blockIdx.x >= 512) {
        int e  = (blockIdx.x - 512) * 256 + t;   // float4 id, 81920 total
        int e4 = e << 2;
        const float* src; unsigned short* dst; int off;
        if (e4 < DC * DV)              { src = Wp; dst = Wpb; off = e4; }
        else if (e4 < DC * (DV + DC))  { src = W1; dst = W1b; off = e4 - DC * DV; }
        else                           { src = W2; dst = W2b; off = e4 - DC * (DV + DC); }
        float4 v = *(const float4*)(src + off);
        ushort4 o;
        o.x = f2bf(v.x); o.y = f2bf(v.y); o.z = f2bf(v.z); o.w = f2bf(v.w);
        *(ushort4*)(dst + off) = o;
        return;
    }

    __shared__ float shX[1024], shY[1024], shZ[1024];
    __shared__ double rb[4][8];

    const int bid  = blockIdx.x;
    const int b    = bid >> 7;          // 128 tiles per batch
    const int tile = bid & 127;

    double n2sx[8], n2sy[8], n2sz[8];
    {
        const float* sp = seed_xyz + ((size_t)b * NS + tile * 8) * 3;
        #pragma unroll
        for (int ss = 0; ss < 8; ++ss) {
            n2sx[ss] = -2.0 * (double)sp[ss * 3 + 0];
            n2sy[ss] = -2.0 * (double)sp[ss * 3 + 1];
            n2sz[ss] = -2.0 * (double)sp[ss * 3 + 2];
        }
    }

    const float* pb = pts + (size_t)b * KP * 3;
    double best[8];
    #pragma unroll
    for (int ss = 0; ss < 8; ++ss) best[ss] = 1e300;

    for (int kt = 0; kt < KP; kt += 1024) {
        #pragma unroll
        for (int q = 0; q < 4; ++q) {
            int i = t + q * 256;
            const float* pp = pb + (size_t)(kt + i) * 3;
            shX[i] = pp[0]; shY[i] = pp[1]; shZ[i] = pp[2];
        }
        __syncthreads();
        #pragma unroll 2
        for (int q = 0; q < 4; ++q) {
            int kl = t + (q << 8);
            double px = (double)shX[kl];
            double py = (double)shY[kl];
            double pz = (double)shZ[kl];
            double h  = fma(px, px, fma(py, py, pz * pz));
            long long kidx = (long long)(kt + kl);
            #pragma unroll
            for (int ss = 0; ss < 8; ++ss) {
                double acc = fma(n2sx[ss], px, h);
                acc = fma(n2sy[ss], py, acc);
                acc = fma(n2sz[ss], pz, acc);
                long long bits = __double_as_longlong(acc);
                bits = (bits & 0xFFFFFFFFFFFFE000LL) | kidx;
                best[ss] = fmin(best[ss], __longlong_as_double(bits));
            }
        }
        __syncthreads();
    }

    #pragma unroll
    for (int o = 1; o < 64; o <<= 1) {
        #pragma unroll
        for (int ss = 0; ss < 8; ++ss)
            best[ss] = fmin(best[ss], __shfl_xor(best[ss], o));
    }
    const int w = t >> 6, l = t & 63;
    if (l == 0) {
        #pragma unroll
        for (int ss = 0; ss < 8; ++ss) rb[w][ss] = best[ss];
    }
    __syncthreads();
    if (t < 8) {
        double bb = rb[0][t];
        #pragma unroll
        for (int ww = 1; ww < 4; ++ww) bb = fmin(bb, rb[ww][t]);
        out_idx[b * NS + tile * 8 + t] =
            (int)(__double_as_longlong(bb) & 0x1FFFLL);
    }
}

// ---------------------------------------------------------------------------
// K2: sieve v2 — contiguous feat stream with on-the-fly column selection.
// FIX vs R4: the hot loop's vmcnt pipeline now contains ONLY the streaming
// loads (static, 8-deep). Selected values go to LDS (ds_write -> lgkmcnt,
// does not pollute vmcnt accounting); ALL global stores happen once in the
// epilogue. R4's data-dependent global stores inside the pipeline forced
// per-row s_waitcnt vmcnt(0) -> 0.5 TB/s.
// grid = 4 b x 4 k-slabs(2048) x 32 c-groups(24 rows) = 512 blocks, 512 thr,
// 2 blocks/CU (LDS 64 KB). Per row the block reads 8 KB contiguous (1 f32x4
// per thread). Entries (seeds with argmin-k in slab) are chained per k-slot;
// each thread hoists its 4 chain heads to registers. Same f2bf values to the
// same Gb slots as before -> mega input bitwise identical.
// ---------------------------------------------------------------------------
__global__ __launch_bounds__(512, 4) void sieve_kernel(
    const float* __restrict__ feat, const int* __restrict__ idx,
    unsigned short* __restrict__ Gb)
{
    __shared__ int head[2048];                      // slab-k -> first entry
    __shared__ int enxt[1024];                      // entry -> next entry
    __shared__ int eseed[1024];                     // entry -> seed id
    __shared__ alignas(16) unsigned short sel[1024 * 24];  // entry x row
    __shared__ int nent;

    const int bid = blockIdx.x;
    const int b   = bid >> 7;            // 128 blocks per batch
    const int sl  = (bid >> 5) & 3;
    const int cg  = bid & 31;
    const int k0  = sl * 2048;
    const int c0  = cg * 24;
    const int t   = threadIdx.x;

    const float* fb = feat + ((size_t)(b * DV + c0)) * KP + k0 + t * 4;
    auto ld = [&](int r) -> f32x4 {
        return *(const f32x4*)(fb + (size_t)r * KP);
    };

    // issue the first pipeline octet immediately (overlaps the list build)
    f32x4 v0 = ld(0), v1 = ld(1), v2 = ld(2), v3 = ld(3);
    f32x4 v4 = ld(4), v5 = ld(5), v6 = ld(6), v7 = ld(7);

    #pragma unroll
    for (int i = 0; i < 4; ++i) head[t + i * 512] = -1;
    if (t == 0) nent = 0;
    __syncthreads();
    #pragma unroll
    for (int i = 0; i < 2; ++i) {
        int sd = t + i * 512;
        int k  = idx[b * NS + sd];
        if (k >= k0 && k < k0 + 2048) {
            int p = atomicAdd(&nent, 1);
            eseed[p] = sd;
            enxt[p]  = atomicExch(&head[k - k0], p);
        }
    }
    __syncthreads();

    // row-invariant chain heads for this thread's 4 k positions
    const int h0 = head[t * 4 + 0];
    const int h1 = head[t * 4 + 1];
    const int h2 = head[t * 4 + 2];
    const int h3 = head[t * 4 + 3];

    auto walk = [&](float x, int p, int r) {
        unsigned short u = f2bf(x);
        while (p >= 0) { sel[p * 24 + r] = u; p = enxt[p]; }
    };
    auto proc = [&](f32x4 v, int r) {
        walk(v[0], h0, r); walk(v[1], h1, r);
        walk(v[2], h2, r); walk(v[3], h3, r);
    };

    // 24 rows, 8-deep register pipeline; vmcnt queue = loads only (static)
    for (int r = 0; r < 24; r += 8) {
        proc(v0, r + 0); if (r +  8 < 24) v0 = ld(r +  8);
        proc(v1, r + 1); if (r +  9 < 24) v1 = ld(r +  9);
        proc(v2, r + 2); if (r + 10 < 24) v2 = ld(r + 10);
        proc(v3, r + 3); if (r + 11 < 24) v3 = ld(r + 11);
        proc(v4, r + 4); if (r + 12 < 24) v4 = ld(r + 12);
        proc(v5, r + 5); if (r + 13 < 24) v5 = ld(r + 13);
        proc(v6, r + 6); if (r + 14 < 24) v6 = ld(r + 14);
        proc(v7, r + 7); if (r + 15 < 24) v7 = ld(r + 15);
    }
    __syncthreads();

    // epilogue: one coalesced 48-B store per entry (all vmem waits done here)
    const int ne = nent;
    for (int i = t; i < ne; i += 512) {
        const unsigned short* s = &sel[i * 24];
        unsigned short* g = Gb + ((size_t)b * NS + eseed[i]) * DV + c0;
        *(bf16x8*)(g)      = *(const bf16x8*)(s);
        *(bf16x8*)(g + 8)  = *(const bf16x8*)(s + 8);
        *(bf16x8*)(g + 16) = *(const bf16x8*)(s + 16);
    }
}

// ---------------------------------------------------------------------------
// K3: mega GEMM chain (verified version, unchanged). per block = (batch,
// 16 seeds), 8 waves. MFMA frag: A row=lane&15,k=(lane>>4)*8+j ;
// B col=lane&15; C/D col=lane&15, row=(lane>>4)*4+reg. fg blend operand
// prefetched at kernel start so its HBM latency hides under the GEMM chain.
// ---------------------------------------------------------------------------
__global__ __launch_bounds__(512) void mega_kernel(
    const unsigned short* __restrict__ Gb,
    const float* __restrict__ fg,
    const unsigned short* __restrict__ Wpb, const float* __restrict__ bp,
    const unsigned short* __restrict__ W1b, const float* __restrict__ b1,
    const unsigned short* __restrict__ W2b, const float* __restrict__ b2,
    float* __restrict__ out)
{
    __shared__ alignas(16) unsigned short GtT[16][776];
    __shared__ alignas(16) unsigned short XT[16][264];
    __shared__ alignas(16) unsigned short HT[16][264];
    __shared__ float LNs[8][16];
    __shared__ float LNq[8][16];

    const int bid  = blockIdx.x;
    const int b    = bid >> 6;
    const int tile = bid & 63;
    const int n0   = tile * 16;
    const int t    = threadIdx.x;
    const int w    = t >> 6;
    const int l    = t & 63;
    const int col  = l & 15;
    const int kq   = l >> 4;

    // prefetch blend operand (consumed in epilogue; latency hidden)
    const float* fgb = fg + (size_t)b * DC * NS;
    float fgv[8];
    #pragma unroll
    for (int r = 0; r < 4; ++r) {
        int ch0 = w * 32 + kq * 4 + r;
        fgv[r]     = fgb[(size_t)ch0 * NS + n0 + col];
        fgv[4 + r] = fgb[(size_t)(ch0 + 16) * NS + n0 + col];
    }

    for (int i = t; i < 1536; i += 512) {
        int row = i / 96, c8 = (i % 96) * 8;
        *(bf16x8*)&GtT[row][c8] =
            *(const bf16x8*)&Gb[((size_t)b * NS + n0 + row) * DV + c8];
    }
    __syncthreads();

    // ---- GEMM1: K = 768 ----
    f32x4 acc0 = {0.f, 0.f, 0.f, 0.f};
    f32x4 acc1 = {0.f, 0.f, 0.f, 0.f};
    {
        const unsigned short* A0 = Wpb + (size_t)(w * 32 + col) * DV;
        const unsigned short* A1 = Wpb + (size_t)(w * 32 + 16 + col) * DV;
        #pragma unroll 4
        for (int ks = 0; ks < 24; ++ks) {
            int kb = ks * 32 + kq * 8;
            bf16x8 bf = *(const bf16x8*)&GtT[col][kb];
            bf16x8 a0 = *(const bf16x8*)&A0[kb];
            bf16x8 a1 = *(const bf16x8*)&A1[kb];
            acc0 = __builtin_amdgcn_mfma_f32_16x16x32_bf16(a0, bf, acc0, 0, 0, 0);
            acc1 = __builtin_amdgcn_mfma_f32_16x16x32_bf16(a1, bf, acc1, 0, 0, 0);
        }
    }

    // ---- bias + LayerNorm over channels ----
    float vals[8];
    float s = 0.f, q = 0.f;
    #pragma unroll
    for (int r = 0; r < 4; ++r) {
        int ch0 = w * 32 + kq * 4 + r;
        float v0 = acc0[r] + bp[ch0];
        float v1 = acc1[r] + bp[ch0 + 16];
        vals[r]     = v0;
        vals[4 + r] = v1;
        s += v0 + v1;
        q += v0 * v0 + v1 * v1;
    }
    s += __shfl_xor(s, 16); s += __shfl_xor(s, 32);
    q += __shfl_xor(q, 16); q += __shfl_xor(q, 32);
    if (l < 16) { LNs[w][l] = s; LNq[w][l] = q; }
    __syncthreads();
    float S = 0.f, Q = 0.f;
    #pragma unroll
    for (int ww = 0; ww < 8; ++ww) { S += LNs[ww][col]; Q += LNq[ww][col]; }
    float mu   = S * (1.0f / DC);
    float rstd = rsqrtf(Q * (1.0f / DC) - mu * mu + LN_EPS);
    {
        ushort4 p0, p1;
        p0.x = f2bf((vals[0] - mu) * rstd);
        p0.y = f2bf((vals[1] - mu) * rstd);
        p0.z = f2bf((vals[2] - mu) * rstd);
        p0.w = f2bf((vals[3] - mu) * rstd);
        p1.x = f2bf((vals[4] - mu) * rstd);
        p1.y = f2bf((vals[5] - mu) * rstd);
        p1.z = f2bf((vals[6] - mu) * rstd);
        p1.w = f2bf((vals[7] - mu) * rstd);
        *(ushort4*)&XT[col][w * 32 + kq * 4]      = p0;
        *(ushort4*)&XT[col][w * 32 + 16 + kq * 4] = p1;
    }
    __syncthreads();

    // ---- GEMM2: H = relu(W1 @ X_ln + b1) ----
    acc0 = (f32x4){0.f, 0.f, 0.f, 0.f};
    acc1 = (f32x4){0.f, 0.f, 0.f, 0.f};
    {
        const unsigned short* A0 = W1b + (size_t)(w * 32 + col) * DC;
        const unsigned short* A1 = W1b + (size_t)(w * 32 + 16 + col) * DC;
        #pragma unroll
        for (int ks = 0; ks < 8; ++ks) {
            int kb = ks * 32 + kq * 8;
            bf16x8 bf = *(const bf16x8*)&XT[col][kb];
            bf16x8 a0 = *(const bf16x8*)&A0[kb];
            bf16x8 a1 = *(const bf16x8*)&A1[kb];
            acc0 = __builtin_amdgcn_mfma_f32_16x16x32_bf16(a0, bf, acc0, 0, 0, 0);
            acc1 = __builtin_amdgcn_mfma_f32_16x16x32_bf16(a1, bf, acc1, 0, 0, 0);
        }
    }
    {
        ushort4 p0, p1;
        int ch0 = w * 32 + kq * 4;
        p0.x = f2bf(fmaxf(acc0[0] + b1[ch0 + 0], 0.f));
        p0.y = f2bf(fmaxf(acc0[1] + b1[ch0 + 1], 0.f));
        p0.z = f2bf(fmaxf(acc0[2] + b1[ch0 + 2], 0.f));
        p0.w = f2bf(fmaxf(acc0[3] + b1[ch0 + 3], 0.f));
        p1.x = f2bf(fmaxf(acc1[0] + b1[ch0 + 16], 0.f));
        p1.y = f2bf(fmaxf(acc1[1] + b1[ch0 + 17], 0.f));
        p1.z = f2bf(fmaxf(acc1[2] + b1[ch0 + 18], 0.f));
        p1.w = f2bf(fmaxf(acc1[3] + b1[ch0 + 19], 0.f));
        *(ushort4*)&HT[col][ch0]      = p0;
        *(ushort4*)&HT[col][ch0 + 16] = p1;
    }
    __syncthreads();

    // ---- GEMM3 + blend + store ----
    acc0 = (f32x4){0.f, 0.f, 0.f, 0.f};
    acc1 = (f32x4){0.f, 0.f, 0.f, 0.f};
    {
        const unsigned short* A0 = W2b + (size_t)(w * 32 + col) * DC;
        const unsigned short* A1 = W2b + (size_t)(w * 32 + 16 + col) * DC;
        #pragma unroll
        for (int ks = 0; ks < 8; ++ks) {
            int kb = ks * 32 + kq * 8;
            bf16x8 bf = *(const bf16x8*)&HT[col][kb];
            bf16x8 a0 = *(const bf16x8*)&A0[kb];
            bf16x8 a1 = *(const bf16x8*)&A1[kb];
            acc0 = __builtin_amdgcn_mfma_f32_16x16x32_bf16(a0, bf, acc0, 0, 0, 0);
            acc1 = __builtin_amdgcn_mfma_f32_16x16x32_bf16(a1, bf, acc1, 0, 0, 0);
        }
    }
    {
        float* ob = out + (size_t)b * DC * NS;
        #pragma unroll
        for (int r = 0; r < 4; ++r) {
            int ch0 = w * 32 + kq * 4 + r;
            int ch1 = ch0 + 16;
            size_t o0 = (size_t)ch0 * NS + n0 + col;
            size_t o1 = (size_t)ch1 * NS + n0 + col;
            ob[o0] = 0.5f * fgv[r]     + 0.5f * (acc0[r] + b2[ch0]);
            ob[o1] = 0.5f * fgv[4 + r] + 0.5f * (acc1[r] + b2[ch1]);
        }
    }
}

extern "C" void kernel_launch(void* const* d_in, const int* in_sizes, int n_in,
                              void* d_out, int out_size, void* d_ws, size_t ws_size,
                              hipStream_t stream)
{
    (void)in_sizes; (void)n_in; (void)out_size; (void)ws_size;
    const float* seed_xyz = (const float*)d_in[1];
    const float* pts      = (const float*)d_in[2];
    const float* feat     = (const float*)d_in[3];
    const float* fgn      = (const float*)d_in[4];
    const float* Wp       = (const float*)d_in[5];
    const float* bp       = (const float*)d_in[6];
    const float* W1       = (const float*)d_in[7];
    const float* b1       = (const float*)d_in[8];
    const float* W2       = (const float*)d_in[9];
    const float* b2       = (const float*)d_in[10];
    float* out = (float*)d_out;

    // workspace layout (16B aligned):
    //   idx  @ 0        (16 KB)
    //   Wpb  @ 16384    (384 KB)
    //   W1b  @ 409600   (128 KB)
    //   W2b  @ 540672   (128 KB)
    //   Gb   @ 671744   (6.29 MB bf16 [B][NS][DV])
    char* ws = (char*)d_ws;
    int*            idx = (int*)ws;
    unsigned short* Wpb = (unsigned short*)(ws + 16384);
    unsigned short* W1b = (unsigned short*)(ws + 409600);
    unsigned short* W2b = (unsigned short*)(ws + 540672);
    unsigned short* Gb  = (unsigned short*)(ws + 671744);

    argmin_prep_kernel<<<dim3(832), dim3(256), 0, stream>>>(
        seed_xyz, pts, idx, Wp, W1, W2, Wpb, W1b, W2b);
    sieve_kernel<<<dim3(512), dim3(512), 0, stream>>>(feat, idx, Gb);
    mega_kernel<<<dim3(BB * (NS / 16)), dim3(512), 0, stream>>>(
        Gb, fgn, Wpb, bp, W1b, b1, W2b, b2, out);
}